// Round 3
// baseline (425.758 us; speedup 1.0000x reference)
//
#include <hip/hip_runtime.h>
#include <math.h>

#define BB 64
#define QQ 32
#define DD 4096
#define EE 300
#define EP 304          // K padded to 304 (pad region of qn is zero)
#define NB 30
#define TD 512          // doc rows per block
#define NDT (DD/TD)     // 8
#define KC 16           // floats per K-chunk
#define NCH (EP/KC)     // 19 chunks
#define NREP 2          // LDS histogram replicas

// ---------------- prep: normalize query rows, gate logits ----------------
__global__ __launch_bounds__(64) void drmm_prep(const float* __restrict__ query,
                                                const float* __restrict__ Wg,
                                                const float* __restrict__ bg,
                                                float* __restrict__ qn,
                                                float* __restrict__ glog) {
    const int row  = blockIdx.x;          // b*32+q
    const int lane = threadIdx.x;         // 0..63
    const float* src = query + (size_t)row * EE;
    float ss = 0.f;
    for (int e = lane; e < EE; e += 64) { float x = src[e]; ss += x * x; }
    for (int o = 1; o < 64; o <<= 1) ss += __shfl_xor(ss, o);
    const float inv = 1.0f / sqrtf(ss);
    float* dst = qn + (size_t)row * EP;
    float gd = 0.f;
    for (int e = lane; e < EE; e += 64) {
        float xq = src[e] * inv;
        dst[e] = xq;
        gd += xq * Wg[e];
    }
    for (int e = EE + lane; e < EP; e += 64) dst[e] = 0.f;   // zero pad 300..303
    for (int o = 1; o < 64; o <<= 1) gd += __shfl_xor(gd, o);
    if (lane == 0) glog[row] = gd + bg[0];
}

// ---------------- main: interaction + histogram ----------------
// 256 threads = 4 waves. Wave wv owns q-octet [8wv, 8wv+8). Lane td owns 8 doc
// rows {td + 64j}. Doc chunk [512 rows][16 floats] + qn chunk [32 q][16 floats]
// double-buffered in LDS via global_load_lds, counted vmcnt(10).
__global__ __launch_bounds__(256, 2) void drmm_main(const float* __restrict__ doc,
                                                    const int* __restrict__ qlen,
                                                    const float* __restrict__ qn_ws,
                                                    int* __restrict__ ghist) {
    __shared__ __align__(16) float s_doc[2][TD * KC];   // 2 x 32 KB
    __shared__ __align__(16) float s_qnc[2][QQ * KC];   // 2 x 2 KB
    __shared__ int s_hist[NREP][QQ][31];                // 7.75 KB

    const int b     = blockIdx.x >> 3;
    const int dt    = blockIdx.x & 7;
    const int len   = qlen[b];
    if (len == 0) return;               // hist stays zero for this b

    const int tid = threadIdx.x;
    const int wv  = tid >> 6;           // q-octet
    const int td  = tid & 63;
    const bool wactive = (wv * 8) < len;

    const float* docb = doc + ((size_t)b * DD + dt * TD) * EE;
    const float* qnb  = qn_ws + (size_t)b * QQ * EP;

    // precompute doc-stage row pointers and swizzled slot offsets
    // slot S = i*256 + tid; row r = S>>2; phys slot s' = S&3;
    // logical k-quad k4l = s' ^ ((r>>1)&3)  (inverse-swizzled source, linear dest)
    const float* rowp[8];
    int k4off[8];                       // 4*k4l (floats)
    #pragma unroll
    for (int i = 0; i < 8; ++i) {
        int S  = i * 256 + tid;
        int r  = S >> 2;
        int k4l = (S & 3) ^ ((r >> 1) & 3);
        rowp[i]  = docb + (size_t)r * EE;
        k4off[i] = 4 * k4l;
    }
    // qn chunk: 128 slots, each wave stages all redundantly (uniform vmcnt)
    const float* qg0 = qnb + (td >> 2) * EP + (td & 3) * 4;
    const float* qg1 = qnb + (16 + (td >> 2)) * EP + (td & 3) * 4;

    auto STAGE = [&](int c, int buf) {
        #pragma unroll
        for (int i = 0; i < 8; ++i) {
            int kk = c * KC + k4off[i];
            if (kk >= EE) kk = 0;       // redirect pad slot in-bounds (qn pad=0)
            __builtin_amdgcn_global_load_lds(
                (const __attribute__((address_space(1))) void*)(rowp[i] + kk),
                (__attribute__((address_space(3))) void*)&s_doc[buf][(i * 256 + wv * 64) * 4],
                16, 0, 0);
        }
        __builtin_amdgcn_global_load_lds(
            (const __attribute__((address_space(1))) void*)(qg0 + c * KC),
            (__attribute__((address_space(3))) void*)&s_qnc[buf][0], 16, 0, 0);
        __builtin_amdgcn_global_load_lds(
            (const __attribute__((address_space(1))) void*)(qg1 + c * KC),
            (__attribute__((address_space(3))) void*)&s_qnc[buf][64 * 4], 16, 0, 0);
    };

    STAGE(0, 0);

    for (int s = tid; s < NREP * QQ * 31; s += 256) ((int*)s_hist)[s] = 0;
    asm volatile("s_waitcnt lgkmcnt(0)" ::: "memory");

    float acc[8][8];
    #pragma unroll
    for (int i = 0; i < 8; ++i)
        #pragma unroll
        for (int j = 0; j < 8; ++j) acc[i][j] = 0.f;
    float ssq[8];
    #pragma unroll
    for (int j = 0; j < 8; ++j) ssq[j] = 0.f;

    const int key = (td >> 1) & 3;      // read-side swizzle key (rows td+64j: (row>>1)&3 == key)
    int cur = 0;

    for (int c = 0; c < NCH; ++c) {
        if (c + 1 < NCH) {
            STAGE(c + 1, cur ^ 1);
            asm volatile("s_waitcnt vmcnt(10)" ::: "memory");
        } else {
            asm volatile("s_waitcnt vmcnt(0)" ::: "memory");
        }
        __builtin_amdgcn_s_barrier();

        if (wactive) {
            #pragma unroll
            for (int k4 = 0; k4 < 4; ++k4) {
                float4 dv[8];
                #pragma unroll
                for (int j = 0; j < 8; ++j)
                    dv[j] = *(const float4*)&s_doc[cur][(td + 64 * j) * KC + 4 * (k4 ^ key)];
                if (c * KC + 4 * k4 < EE) {   // skip pad slot in norm
                    #pragma unroll
                    for (int j = 0; j < 8; ++j)
                        ssq[j] += dv[j].x * dv[j].x + dv[j].y * dv[j].y
                                + dv[j].z * dv[j].z + dv[j].w * dv[j].w;
                }
                #pragma unroll
                for (int i = 0; i < 8; ++i) {
                    float4 qv = *(const float4*)&s_qnc[cur][(wv * 8 + i) * KC + 4 * k4];
                    #pragma unroll
                    for (int j = 0; j < 8; ++j) {
                        acc[i][j] += qv.x * dv[j].x;
                        acc[i][j] += qv.y * dv[j].y;
                        acc[i][j] += qv.z * dv[j].z;
                        acc[i][j] += qv.w * dv[j].w;
                    }
                }
            }
        }
        __builtin_amdgcn_s_barrier();
        cur ^= 1;
    }
    __syncthreads();

    if (wactive) {
        float rinv[8];
        #pragma unroll
        for (int j = 0; j < 8; ++j) rinv[j] = 1.0f / sqrtf(ssq[j]);
        const int rep = td & (NREP - 1);
        #pragma unroll
        for (int i = 0; i < 8; ++i) {
            const int q = wv * 8 + i;
            if (q < len) {                   // wave-uniform
                #pragma unroll
                for (int j = 0; j < 8; ++j) {
                    float sim = acc[i][j] * rinv[j];
                    int bin = (int)floorf((sim + 1.0f) * 15.0f);
                    bin = bin < 0 ? 0 : (bin > 29 ? 29 : bin);
                    atomicAdd(&s_hist[rep][q][bin], 1);
                }
            }
        }
    }
    __syncthreads();

    for (int s = tid; s < QQ * NB; s += 256) {
        const int q = s / NB, bin = s % NB;
        int tot = 0;
        #pragma unroll
        for (int r = 0; r < NREP; ++r) tot += s_hist[r][q][bin];
        if (tot) atomicAdd(&ghist[((size_t)b * QQ + q) * NB + bin], tot);
    }
}

// ---------------- final: log1p + FFN + softmax gate + weighted sum ----------------
__global__ __launch_bounds__(64) void drmm_final(const int* __restrict__ ghist,
                                                 const float* __restrict__ glog,
                                                 const float* __restrict__ W1,
                                                 const float* __restrict__ b1,
                                                 const float* __restrict__ W2,
                                                 const float* __restrict__ b2,
                                                 const float* __restrict__ W3,
                                                 const float* __restrict__ b3,
                                                 float* __restrict__ out) {
    const int b = blockIdx.x;
    const int lane = threadIdx.x;       // lanes 0..31 carry q
    float z = 0.f, lg = -1e30f;
    if (lane < QQ) {
        const int* hrow = ghist + ((size_t)b * QQ + lane) * NB;
        float h[NB];
        #pragma unroll
        for (int v = 0; v < NB; ++v) h[v] = log1pf((float)hrow[v]);
        float t1[5];
        #pragma unroll
        for (int u = 0; u < 5; ++u) {
            float s = b1[u];
            #pragma unroll
            for (int v = 0; v < NB; ++v) s += W1[u * NB + v] * h[v];
            t1[u] = tanhf(s);
        }
        float s2 = b2[0];
        #pragma unroll
        for (int u = 0; u < 5; ++u) s2 += W2[u] * t1[u];
        z = tanhf(W3[0] * tanhf(s2) + b3[0]);
        lg = glog[b * QQ + lane];
    }
    float m = lg;
    for (int o = 16; o >= 1; o >>= 1) m = fmaxf(m, __shfl_xor(m, o));
    float e = (lane < QQ) ? expf(lg - m) : 0.f;
    float s = e;
    for (int o = 16; o >= 1; o >>= 1) s += __shfl_xor(s, o);
    float w = z * (e / s);
    for (int o = 16; o >= 1; o >>= 1) w += __shfl_xor(w, o);
    if (lane == 0) out[b] = w;
}

extern "C" void kernel_launch(void* const* d_in, const int* in_sizes, int n_in,
                              void* d_out, int out_size, void* d_ws, size_t ws_size,
                              hipStream_t stream) {
    const float* query = (const float*)d_in[0];
    const float* doc   = (const float*)d_in[1];
    const int*   qlen  = (const int*)d_in[2];
    const float* W1    = (const float*)d_in[3];
    const float* b1    = (const float*)d_in[4];
    const float* W2    = (const float*)d_in[5];
    const float* b2    = (const float*)d_in[6];
    const float* W3    = (const float*)d_in[7];
    const float* b3    = (const float*)d_in[8];
    const float* Wg    = (const float*)d_in[9];
    const float* bg    = (const float*)d_in[10];
    float* out = (float*)d_out;

    float* qn   = (float*)d_ws;                       // [64][32][304]
    float* glog = qn + (size_t)BB * QQ * EP;          // [2048]
    int*   hist = (int*)(glog + BB * QQ);             // [64][32][30]

    hipMemsetAsync(hist, 0, (size_t)BB * QQ * NB * sizeof(int), stream);
    hipLaunchKernelGGL(drmm_prep, dim3(BB * QQ), dim3(64), 0, stream,
                       query, Wg, bg, qn, glog);
    hipLaunchKernelGGL(drmm_main, dim3(BB * NDT), dim3(256), 0, stream,
                       doc, qlen, qn, hist);
    hipLaunchKernelGGL(drmm_final, dim3(BB), dim3(64), 0, stream,
                       hist, glog, W1, b1, W2, b2, W3, b3, out);
}

// Round 4
// 253.329 us; speedup vs baseline: 1.6807x; 1.6807x over previous
//
#include <hip/hip_runtime.h>
#include <math.h>

#define BB 64
#define QQ 32
#define DD 4096
#define EE 300
#define EP 304          // K padded to 304 (pad region of qn is zero)
#define NB 30
#define TD 256          // doc rows per block
#define NDT (DD/TD)     // 16
#define KC 16           // floats per K-chunk
#define NCH (EP/KC)     // 19 chunks
#define NREP 4          // LDS histogram replicas

// ---------------- prep: normalize query rows, gate logits ----------------
__global__ __launch_bounds__(64) void drmm_prep(const float* __restrict__ query,
                                                const float* __restrict__ Wg,
                                                const float* __restrict__ bg,
                                                float* __restrict__ qn,
                                                float* __restrict__ glog) {
    const int row  = blockIdx.x;          // b*32+q
    const int lane = threadIdx.x;         // 0..63
    const float* src = query + (size_t)row * EE;
    float ss = 0.f;
    for (int e = lane; e < EE; e += 64) { float x = src[e]; ss += x * x; }
    for (int o = 1; o < 64; o <<= 1) ss += __shfl_xor(ss, o);
    const float inv = 1.0f / sqrtf(ss);
    float* dst = qn + (size_t)row * EP;
    float gd = 0.f;
    for (int e = lane; e < EE; e += 64) {
        float xq = src[e] * inv;
        dst[e] = xq;
        gd += xq * Wg[e];
    }
    for (int e = EE + lane; e < EP; e += 64) dst[e] = 0.f;   // zero pad 300..303
    for (int o = 1; o < 64; o <<= 1) gd += __shfl_xor(gd, o);
    if (lane == 0) glog[row] = gd + bg[0];
}

// ---------------- main: interaction + histogram ----------------
// 256 threads = 4 waves; wave wv owns q-octet [8wv,8wv+8), lane td owns doc
// rows {td+64j, j<4}. Doc chunk [256 rows][16 floats] + qn chunk [32 q][16]
// double-buffered via global_load_lds, counted vmcnt(6). 51.5 KB LDS ->
// 3 blocks/CU (3 waves/SIMD).
__global__ __launch_bounds__(256, 3) void drmm_main(const float* __restrict__ doc,
                                                    const int* __restrict__ qlen,
                                                    const float* __restrict__ qn_ws,
                                                    int* __restrict__ ghist) {
    __shared__ __align__(16) float s_doc[2][TD * KC];   // 2 x 16 KB
    __shared__ __align__(16) float s_qnc[2][QQ * KC];   // 2 x 2 KB
    __shared__ int s_hist[NREP][QQ][31];                // 15.5 KB

    const int b   = blockIdx.x >> 4;
    const int dt  = blockIdx.x & 15;
    const int len = qlen[b];
    if (len == 0) return;               // hist stays zero for this b

    const int tid = threadIdx.x;
    const int wv  = tid >> 6;           // q-octet
    const int td  = tid & 63;
    const bool wactive = (wv * 8) < len;

    const float* docb = doc + ((size_t)b * DD + dt * TD) * EE;
    const float* qnb  = qn_ws + (size_t)b * QQ * EP;

    // stage chunk c into buffer buf: 4 doc slots + 2 qn slots per thread.
    // doc slot S = i*256+tid: row r=S>>2, phys quad p=S&3 holds logical quad
    // p ^ ((r>>1)&3) (inverse-swizzled source, linear LDS dest).
    auto STAGE = [&](int c, int buf) {
        #pragma unroll
        for (int i = 0; i < 4; ++i) {
            int S   = i * 256 + tid;
            int r   = S >> 2;
            int k4l = (S & 3) ^ ((r >> 1) & 3);
            int kk  = c * KC + 4 * k4l;
            if (kk >= EE) kk = 0;       // pad quad: redirect in-bounds (qn pad=0)
            __builtin_amdgcn_global_load_lds(
                (const __attribute__((address_space(1))) void*)(docb + (size_t)r * EE + kk),
                (__attribute__((address_space(3))) void*)&s_doc[buf][(i * 256 + wv * 64) * 4],
                16, 0, 0);
        }
        // qn: 128 slots, each wave stages all 128 redundantly (uniform vmcnt)
        #pragma unroll
        for (int i = 0; i < 2; ++i) {
            int s = i * 64 + td;        // slot: q = s>>2, quad = s&3
            __builtin_amdgcn_global_load_lds(
                (const __attribute__((address_space(1))) void*)
                    (qnb + (size_t)(s >> 2) * EP + c * KC + (s & 3) * 4),
                (__attribute__((address_space(3))) void*)&s_qnc[buf][(i * 64 + wv * 0) * 4 + i * 0 + (i * 64) * 4],
                16, 0, 0);
        }
    };

    STAGE(0, 0);

    for (int s = tid; s < NREP * QQ * 31; s += 256) ((int*)s_hist)[s] = 0;
    asm volatile("s_waitcnt lgkmcnt(0)" ::: "memory");

    float acc[8][4];
    #pragma unroll
    for (int i = 0; i < 8; ++i)
        #pragma unroll
        for (int j = 0; j < 4; ++j) acc[i][j] = 0.f;
    float ssq[4];
    #pragma unroll
    for (int j = 0; j < 4; ++j) ssq[j] = 0.f;

    const int key = (td >> 1) & 3;      // rows td+64j all share (row>>1)&3 == key
    int cur = 0;

    for (int c = 0; c < NCH; ++c) {
        if (c + 1 < NCH) {
            STAGE(c + 1, cur ^ 1);
            asm volatile("s_waitcnt vmcnt(6)" ::: "memory");
        } else {
            asm volatile("s_waitcnt vmcnt(0)" ::: "memory");
        }
        __builtin_amdgcn_s_barrier();

        if (wactive) {
            #pragma unroll
            for (int k4 = 0; k4 < 4; ++k4) {
                float4 dv[4];
                #pragma unroll
                for (int j = 0; j < 4; ++j)
                    dv[j] = *(const float4*)&s_doc[cur][(td + 64 * j) * KC + 4 * (k4 ^ key)];
                if (c * KC + 4 * k4 < EE) {   // pad quad excluded from norm
                    #pragma unroll
                    for (int j = 0; j < 4; ++j)
                        ssq[j] += dv[j].x * dv[j].x + dv[j].y * dv[j].y
                                + dv[j].z * dv[j].z + dv[j].w * dv[j].w;
                }
                #pragma unroll
                for (int i = 0; i < 8; ++i) {
                    float4 qv = *(const float4*)&s_qnc[cur][(wv * 8 + i) * KC + 4 * k4];
                    #pragma unroll
                    for (int j = 0; j < 4; ++j) {
                        acc[i][j] += qv.x * dv[j].x;
                        acc[i][j] += qv.y * dv[j].y;
                        acc[i][j] += qv.z * dv[j].z;
                        acc[i][j] += qv.w * dv[j].w;
                    }
                }
            }
        }
        __builtin_amdgcn_s_barrier();
        cur ^= 1;
    }
    __syncthreads();

    if (wactive) {
        float rinv[4];
        #pragma unroll
        for (int j = 0; j < 4; ++j) rinv[j] = 1.0f / sqrtf(ssq[j]);
        const int rep = td & (NREP - 1);
        #pragma unroll
        for (int i = 0; i < 8; ++i) {
            const int q = wv * 8 + i;
            if (q < len) {                   // wave-uniform
                #pragma unroll
                for (int j = 0; j < 4; ++j) {
                    float sim = acc[i][j] * rinv[j];
                    int bin = (int)floorf((sim + 1.0f) * 15.0f);
                    bin = bin < 0 ? 0 : (bin > 29 ? 29 : bin);
                    atomicAdd(&s_hist[rep][q][bin], 1);
                }
            }
        }
    }
    __syncthreads();

    for (int s = tid; s < QQ * NB; s += 256) {
        const int q = s / NB, bin = s % NB;
        int tot = 0;
        #pragma unroll
        for (int r = 0; r < NREP; ++r) tot += s_hist[r][q][bin];
        if (tot) atomicAdd(&ghist[((size_t)b * QQ + q) * NB + bin], tot);
    }
}

// ---------------- final: log1p + FFN + softmax gate + weighted sum ----------------
__global__ __launch_bounds__(64) void drmm_final(const int* __restrict__ ghist,
                                                 const float* __restrict__ glog,
                                                 const float* __restrict__ W1,
                                                 const float* __restrict__ b1,
                                                 const float* __restrict__ W2,
                                                 const float* __restrict__ b2,
                                                 const float* __restrict__ W3,
                                                 const float* __restrict__ b3,
                                                 float* __restrict__ out) {
    const int b = blockIdx.x;
    const int lane = threadIdx.x;       // lanes 0..31 carry q
    float z = 0.f, lg = -1e30f;
    if (lane < QQ) {
        const int* hrow = ghist + ((size_t)b * QQ + lane) * NB;
        float h[NB];
        #pragma unroll
        for (int v = 0; v < NB; ++v) h[v] = log1pf((float)hrow[v]);
        float t1[5];
        #pragma unroll
        for (int u = 0; u < 5; ++u) {
            float s = b1[u];
            #pragma unroll
            for (int v = 0; v < NB; ++v) s += W1[u * NB + v] * h[v];
            t1[u] = tanhf(s);
        }
        float s2 = b2[0];
        #pragma unroll
        for (int u = 0; u < 5; ++u) s2 += W2[u] * t1[u];
        z = tanhf(W3[0] * tanhf(s2) + b3[0]);
        lg = glog[b * QQ + lane];
    }
    float m = lg;
    for (int o = 16; o >= 1; o >>= 1) m = fmaxf(m, __shfl_xor(m, o));
    float e = (lane < QQ) ? expf(lg - m) : 0.f;
    float s = e;
    for (int o = 16; o >= 1; o >>= 1) s += __shfl_xor(s, o);
    float w = z * (e / s);
    for (int o = 16; o >= 1; o >>= 1) w += __shfl_xor(w, o);
    if (lane == 0) out[b] = w;
}

extern "C" void kernel_launch(void* const* d_in, const int* in_sizes, int n_in,
                              void* d_out, int out_size, void* d_ws, size_t ws_size,
                              hipStream_t stream) {
    const float* query = (const float*)d_in[0];
    const float* doc   = (const float*)d_in[1];
    const int*   qlen  = (const int*)d_in[2];
    const float* W1    = (const float*)d_in[3];
    const float* b1    = (const float*)d_in[4];
    const float* W2    = (const float*)d_in[5];
    const float* b2    = (const float*)d_in[6];
    const float* W3    = (const float*)d_in[7];
    const float* b3    = (const float*)d_in[8];
    const float* Wg    = (const float*)d_in[9];
    const float* bg    = (const float*)d_in[10];
    float* out = (float*)d_out;

    float* qn   = (float*)d_ws;                       // [64][32][304]
    float* glog = qn + (size_t)BB * QQ * EP;          // [2048]
    int*   hist = (int*)(glog + BB * QQ);             // [64][32][30]

    hipMemsetAsync(hist, 0, (size_t)BB * QQ * NB * sizeof(int), stream);
    hipLaunchKernelGGL(drmm_prep, dim3(BB * QQ), dim3(64), 0, stream,
                       query, Wg, bg, qn, glog);
    hipLaunchKernelGGL(drmm_main, dim3(BB * NDT), dim3(256), 0, stream,
                       doc, qlen, qn, hist);
    hipLaunchKernelGGL(drmm_final, dim3(BB), dim3(64), 0, stream,
                       hist, glog, W1, b1, W2, b2, W3, b3, out);
}

// Round 5
// 198.697 us; speedup vs baseline: 2.1428x; 1.2750x over previous
//
#include <hip/hip_runtime.h>
#include <math.h>

#define BB 64
#define QQ 32
#define DD 4096
#define EE 300
#define EP 320          // K padded to 320 (qn pad region is zero)
#define NB 30
#define TD 256          // doc rows per block
#define NDT (DD/TD)     // 16
#define KC 32           // floats per K-chunk
#define NCH (EP/KC)     // 10 chunks
#define NREP 2          // LDS histogram replicas

// ---------------- prep: normalize query rows, gate logits ----------------
__global__ __launch_bounds__(64) void drmm_prep(const float* __restrict__ query,
                                                const float* __restrict__ Wg,
                                                const float* __restrict__ bg,
                                                float* __restrict__ qn,
                                                float* __restrict__ glog) {
    const int row  = blockIdx.x;          // b*32+q
    const int lane = threadIdx.x;         // 0..63
    const float* src = query + (size_t)row * EE;
    float ss = 0.f;
    for (int e = lane; e < EE; e += 64) { float x = src[e]; ss += x * x; }
    for (int o = 1; o < 64; o <<= 1) ss += __shfl_xor(ss, o);
    const float inv = 1.0f / sqrtf(ss);
    float* dst = qn + (size_t)row * EP;
    float gd = 0.f;
    for (int e = lane; e < EE; e += 64) {
        float xq = src[e] * inv;
        dst[e] = xq;
        gd += xq * Wg[e];
    }
    for (int e = EE + lane; e < EP; e += 64) dst[e] = 0.f;   // zero pad 300..319
    for (int o = 1; o < 64; o <<= 1) gd += __shfl_xor(gd, o);
    if (lane == 0) glog[row] = gd + bg[0];
}

// ---------------- main: interaction + histogram ----------------
// 256 threads = 4 waves. Wave wv owns q in {wv, wv+4, ..., wv+28} (interleaved
// so work ~ len is balanced across all 4 SIMDs). Lane td owns doc rows
// {td+64j, j<4}. Doc chunk [256 rows][32 floats] + qn chunk [32 q][32 floats]
// double-buffered via global_load_lds (counted vmcnt(9), never 0 in-loop).
// LDS 81,408 B -> 2 blocks/CU.
__global__ __launch_bounds__(256, 2) void drmm_main(const float* __restrict__ doc,
                                                    const int* __restrict__ qlen,
                                                    const float* __restrict__ qn_ws,
                                                    int* __restrict__ ghist) {
    __shared__ __align__(16) float s_doc[2][TD * KC];   // 2 x 32 KB
    __shared__ __align__(16) float s_qnc[2][QQ * KC];   // 2 x 4 KB
    __shared__ int s_hist[NREP][QQ][NB];                // 7.5 KB

    const int b   = blockIdx.x >> 4;
    const int dt  = blockIdx.x & 15;
    const int len = qlen[b];
    if (len == 0) return;               // hist stays zero for this b

    const int tid = threadIdx.x;
    const int wv  = tid >> 6;           // q-interleave phase
    const int td  = tid & 63;

    const float* docb = doc + ((size_t)b * DD + dt * TD) * EE;
    const float* qnb  = qn_ws + (size_t)b * QQ * EP;

    // stage chunk c into buffer buf.
    // doc: 2048 16B-slots; slot S = i*256+tid -> row r=S>>3, phys quad p=S&7
    //      holding logical quad p ^ (r&7) (inverse-swizzled source, linear dest).
    // qn:  256 slots; slot tid -> q=tid>>3, quad tid&7 (linear, reads broadcast).
    auto STAGE = [&](int c, int buf) {
        #pragma unroll
        for (int i = 0; i < 8; ++i) {
            int S  = i * 256 + tid;
            int r  = S >> 3;
            int l  = (S & 7) ^ (r & 7);
            int kk = c * KC + 4 * l;
            if (kk >= EE) kk = 0;       // pad quad: redirect in-bounds (qn pad=0)
            __builtin_amdgcn_global_load_lds(
                (const __attribute__((address_space(1))) void*)(docb + (size_t)r * EE + kk),
                (__attribute__((address_space(3))) void*)&s_doc[buf][(i * 256 + wv * 64) * 4],
                16, 0, 0);
        }
        {
            int kk = c * KC + (tid & 7) * 4;
            if (kk >= EP) kk = 0;       // never true (kept for safety)
            __builtin_amdgcn_global_load_lds(
                (const __attribute__((address_space(1))) void*)
                    (qnb + (size_t)(tid >> 3) * EP + kk),
                (__attribute__((address_space(3))) void*)&s_qnc[buf][wv * 256],
                16, 0, 0);
        }
    };

    STAGE(0, 0);

    for (int s = tid; s < NREP * QQ * NB; s += 256) ((int*)s_hist)[s] = 0;

    float acc[8][4];
    #pragma unroll
    for (int i = 0; i < 8; ++i)
        #pragma unroll
        for (int j = 0; j < 4; ++j) acc[i][j] = 0.f;
    float ssq[4];
    #pragma unroll
    for (int j = 0; j < 4; ++j) ssq[j] = 0.f;

    const int key = td & 7;             // rows td+64j all share row&7 == td&7
    int cur = 0;

    for (int c = 0; c < NCH; ++c) {
        if (c + 1 < NCH) {
            STAGE(c + 1, cur ^ 1);
            asm volatile("s_waitcnt vmcnt(9)" ::: "memory");
        } else {
            asm volatile("s_waitcnt vmcnt(0)" ::: "memory");
        }
        __builtin_amdgcn_s_barrier();

        #pragma unroll
        for (int k4 = 0; k4 < 8; ++k4) {
            float4 dv[4];
            #pragma unroll
            for (int j = 0; j < 4; ++j)
                dv[j] = *(const float4*)&s_doc[cur][(td + 64 * j) * KC + 4 * (k4 ^ key)];
            if (c * KC + 4 * k4 < EE) {   // pad quads excluded from norm
                #pragma unroll
                for (int j = 0; j < 4; ++j)
                    ssq[j] += dv[j].x * dv[j].x + dv[j].y * dv[j].y
                            + dv[j].z * dv[j].z + dv[j].w * dv[j].w;
            }
            #pragma unroll
            for (int i = 0; i < 8; ++i) {
                if (wv + 4 * i < len) {   // wave-uniform (wv, len uniform)
                    float4 qv = *(const float4*)&s_qnc[cur][(wv + 4 * i) * KC + 4 * k4];
                    #pragma unroll
                    for (int j = 0; j < 4; ++j) {
                        acc[i][j] += qv.x * dv[j].x;
                        acc[i][j] += qv.y * dv[j].y;
                        acc[i][j] += qv.z * dv[j].z;
                        acc[i][j] += qv.w * dv[j].w;
                    }
                }
            }
        }
        __builtin_amdgcn_s_barrier();
        cur ^= 1;
    }
    __syncthreads();

    {
        float rinv[4];
        #pragma unroll
        for (int j = 0; j < 4; ++j) rinv[j] = 1.0f / sqrtf(ssq[j]);
        const int rep = td & (NREP - 1);
        #pragma unroll
        for (int i = 0; i < 8; ++i) {
            const int q = wv + 4 * i;
            if (q < len) {                   // wave-uniform
                #pragma unroll
                for (int j = 0; j < 4; ++j) {
                    float sim = acc[i][j] * rinv[j];
                    int bin = (int)floorf((sim + 1.0f) * 15.0f);
                    bin = bin < 0 ? 0 : (bin > 29 ? 29 : bin);
                    atomicAdd(&s_hist[rep][q][bin], 1);
                }
            }
        }
    }
    __syncthreads();

    for (int s = tid; s < QQ * NB; s += 256) {
        const int q = s / NB, bin = s % NB;
        int tot = 0;
        #pragma unroll
        for (int r = 0; r < NREP; ++r) tot += s_hist[r][q][bin];
        if (tot) atomicAdd(&ghist[((size_t)b * QQ + q) * NB + bin], tot);
    }
}

// ---------------- final: log1p + FFN + softmax gate + weighted sum ----------------
__global__ __launch_bounds__(64) void drmm_final(const int* __restrict__ ghist,
                                                 const float* __restrict__ glog,
                                                 const float* __restrict__ W1,
                                                 const float* __restrict__ b1,
                                                 const float* __restrict__ W2,
                                                 const float* __restrict__ b2,
                                                 const float* __restrict__ W3,
                                                 const float* __restrict__ b3,
                                                 float* __restrict__ out) {
    const int b = blockIdx.x;
    const int lane = threadIdx.x;       // lanes 0..31 carry q
    float z = 0.f, lg = -1e30f;
    if (lane < QQ) {
        const int* hrow = ghist + ((size_t)b * QQ + lane) * NB;
        float h[NB];
        #pragma unroll
        for (int v = 0; v < NB; ++v) h[v] = log1pf((float)hrow[v]);
        float t1[5];
        #pragma unroll
        for (int u = 0; u < 5; ++u) {
            float s = b1[u];
            #pragma unroll
            for (int v = 0; v < NB; ++v) s += W1[u * NB + v] * h[v];
            t1[u] = tanhf(s);
        }
        float s2 = b2[0];
        #pragma unroll
        for (int u = 0; u < 5; ++u) s2 += W2[u] * t1[u];
        z = tanhf(W3[0] * tanhf(s2) + b3[0]);
        lg = glog[b * QQ + lane];
    }
    float m = lg;
    for (int o = 16; o >= 1; o >>= 1) m = fmaxf(m, __shfl_xor(m, o));
    float e = (lane < QQ) ? expf(lg - m) : 0.f;
    float s = e;
    for (int o = 16; o >= 1; o >>= 1) s += __shfl_xor(s, o);
    float w = z * (e / s);
    for (int o = 16; o >= 1; o >>= 1) w += __shfl_xor(w, o);
    if (lane == 0) out[b] = w;
}

extern "C" void kernel_launch(void* const* d_in, const int* in_sizes, int n_in,
                              void* d_out, int out_size, void* d_ws, size_t ws_size,
                              hipStream_t stream) {
    const float* query = (const float*)d_in[0];
    const float* doc   = (const float*)d_in[1];
    const int*   qlen  = (const int*)d_in[2];
    const float* W1    = (const float*)d_in[3];
    const float* b1    = (const float*)d_in[4];
    const float* W2    = (const float*)d_in[5];
    const float* b2    = (const float*)d_in[6];
    const float* W3    = (const float*)d_in[7];
    const float* b3    = (const float*)d_in[8];
    const float* Wg    = (const float*)d_in[9];
    const float* bg    = (const float*)d_in[10];
    float* out = (float*)d_out;

    float* qn   = (float*)d_ws;                       // [64][32][320]
    float* glog = qn + (size_t)BB * QQ * EP;          // [2048]
    int*   hist = (int*)(glog + BB * QQ);             // [64][32][30]

    hipMemsetAsync(hist, 0, (size_t)BB * QQ * NB * sizeof(int), stream);
    hipLaunchKernelGGL(drmm_prep, dim3(BB * QQ), dim3(64), 0, stream,
                       query, Wg, bg, qn, glog);
    hipLaunchKernelGGL(drmm_main, dim3(BB * NDT), dim3(256), 0, stream,
                       doc, qlen, qn, hist);
    hipLaunchKernelGGL(drmm_final, dim3(BB), dim3(64), 0, stream,
                       hist, glog, W1, b1, W2, b2, W3, b3, out);
}

// Round 6
// 184.626 us; speedup vs baseline: 2.3061x; 1.0762x over previous
//
#include <hip/hip_runtime.h>
#include <math.h>

#define BB 64
#define QQ 32
#define DD 4096
#define EE 300
#define EP 304          // qn row stride; floats 300..303 are zero pad
#define NB 30
#define TD 256          // doc rows per block
#define NDT (DD/TD)     // 16
#define KC 16           // floats per K-chunk
#define NCH 19          // 19*16 = 304 >= 300
#define LASTC 18        // last chunk index (has the pad quad)

// ---------------- prep: normalize query rows, gate logits ----------------
__global__ __launch_bounds__(64) void drmm_prep(const float* __restrict__ query,
                                                const float* __restrict__ Wg,
                                                const float* __restrict__ bg,
                                                float* __restrict__ qn,
                                                float* __restrict__ glog) {
    const int row  = blockIdx.x;          // b*32+q
    const int lane = threadIdx.x;         // 0..63
    const float* src = query + (size_t)row * EE;
    float ss = 0.f;
    for (int e = lane; e < EE; e += 64) { float x = src[e]; ss += x * x; }
    for (int o = 1; o < 64; o <<= 1) ss += __shfl_xor(ss, o);
    const float inv = 1.0f / sqrtf(ss);
    float* dst = qn + (size_t)row * EP;
    float gd = 0.f;
    for (int e = lane; e < EE; e += 64) {
        float xq = src[e] * inv;
        dst[e] = xq;
        gd += xq * Wg[e];
    }
    for (int e = EE + lane; e < EP; e += 64) dst[e] = 0.f;   // zero pad 300..303
    for (int o = 1; o < 64; o <<= 1) gd += __shfl_xor(gd, o);
    if (lane == 0) glog[row] = gd + bg[0];
}

// ---------------- main: interaction + histogram ----------------
// 256 threads = 4 waves. Wave wv owns q in {wv, wv+4, ..., wv+28} (interleaved:
// work ~ len balanced across SIMDs); active count na is SCALAR (readfirstlane)
// so masking is s_cbranch, not exec churn. Lane td owns doc rows {td+64j, j<4}.
// Doc chunk [256][16] + qn chunk [32][16] double-buffered via global_load_lds
// (counted vmcnt(6)). LDS exactly 40,960 B -> 4 blocks/CU, grid fully resident.
__global__ __launch_bounds__(256, 4) void drmm_main(const float* __restrict__ doc,
                                                    const int* __restrict__ qlen,
                                                    const float* __restrict__ qn_ws,
                                                    int* __restrict__ ghist) {
    __shared__ __align__(16) float s_doc[2][TD * KC];   // 2 x 16 KB
    __shared__ __align__(16) float s_qnc[2][QQ * KC];   // 2 x 2 KB
    __shared__ int s_hist[QQ][32];                      // 4 KB (2-col pad)

    const int b   = blockIdx.x >> 4;
    const int dt  = blockIdx.x & 15;
    const int len = qlen[b];
    if (len == 0) return;               // hist stays zero for this b

    const int tid  = threadIdx.x;
    const int wv_s = __builtin_amdgcn_readfirstlane(tid >> 6);  // scalar wave id
    const int td   = tid & 63;
    // number of active i (q = wv_s + 4i < len), scalar
    int na = (len - wv_s + 3) >> 2;
    na = na < 0 ? 0 : (na > 8 ? 8 : na);

    const float* docb = doc + ((size_t)b * DD + dt * TD) * EE;
    const float* qnb  = qn_ws + (size_t)b * QQ * EP;

    // stage chunk c into buffer buf.
    // doc: 1024 16B-slots; slot S=i*256+tid -> row r=S>>2, phys quad p=S&3
    //      holding logical quad p ^ ((r>>1)&3) (inverse-swizzled source,
    //      linear LDS dest). qn: 128 slots, staged redundantly by all waves.
    auto STAGE = [&](int c, int buf) {
        #pragma unroll
        for (int i = 0; i < 4; ++i) {
            int S  = i * 256 + tid;
            int r  = S >> 2;
            int l  = (S & 3) ^ ((r >> 1) & 3);
            int kk = c * KC + 4 * l;
            if (kk >= EE) kk = 0;       // pad quad (c=18,l=3): redirect, qn pad=0
            __builtin_amdgcn_global_load_lds(
                (const __attribute__((address_space(1))) void*)(docb + (size_t)r * EE + kk),
                (__attribute__((address_space(3))) void*)&s_doc[buf][(i * 256 + wv_s * 64) * 4],
                16, 0, 0);
        }
        #pragma unroll
        for (int i = 0; i < 2; ++i) {
            int s = i * 64 + td;        // slot: q = s>>2, quad = s&3
            __builtin_amdgcn_global_load_lds(
                (const __attribute__((address_space(1))) void*)
                    (qnb + (size_t)(s >> 2) * EP + c * KC + (s & 3) * 4),
                (__attribute__((address_space(3))) void*)&s_qnc[buf][i * 256],
                16, 0, 0);
        }
    };

    STAGE(0, 0);

    for (int s = tid; s < QQ * 32; s += 256) ((int*)s_hist)[s] = 0;

    float acc[8][4];
    #pragma unroll
    for (int i = 0; i < 8; ++i)
        #pragma unroll
        for (int j = 0; j < 4; ++j) acc[i][j] = 0.f;
    float ssq[4];
    #pragma unroll
    for (int j = 0; j < 4; ++j) ssq[j] = 0.f;

    const int key = (td >> 1) & 3;      // rows td+64j share ((row>>1)&3) == key
    int cur = 0;

    for (int c = 0; c < NCH; ++c) {
        if (c + 1 < NCH) {
            STAGE(c + 1, cur ^ 1);
            asm volatile("s_waitcnt vmcnt(6)" ::: "memory");
        } else {
            asm volatile("s_waitcnt vmcnt(0)" ::: "memory");
        }
        __builtin_amdgcn_s_barrier();

        #pragma unroll
        for (int k4 = 0; k4 < 4; ++k4) {
            float4 dv[4];
            #pragma unroll
            for (int j = 0; j < 4; ++j)
                dv[j] = *(const float4*)&s_doc[cur][(td + 64 * j) * KC + 4 * (k4 ^ key)];
            if (k4 != 3 || c != LASTC) {   // exclude the pad quad from norms
                #pragma unroll
                for (int j = 0; j < 4; ++j)
                    ssq[j] += dv[j].x * dv[j].x + dv[j].y * dv[j].y
                            + dv[j].z * dv[j].z + dv[j].w * dv[j].w;
            }
            #pragma unroll
            for (int i = 0; i < 8; ++i) {
                if (i < na) {            // scalar compare -> s_cbranch, no exec churn
                    float4 qv = *(const float4*)&s_qnc[cur][(wv_s + 4 * i) * KC + 4 * k4];
                    #pragma unroll
                    for (int j = 0; j < 4; ++j) {
                        acc[i][j] += qv.x * dv[j].x;
                        acc[i][j] += qv.y * dv[j].y;
                        acc[i][j] += qv.z * dv[j].z;
                        acc[i][j] += qv.w * dv[j].w;
                    }
                }
            }
        }
        __builtin_amdgcn_s_barrier();
        cur ^= 1;
    }
    __syncthreads();

    {
        float rinv[4];
        #pragma unroll
        for (int j = 0; j < 4; ++j) rinv[j] = 1.0f / sqrtf(ssq[j]);
        #pragma unroll
        for (int i = 0; i < 8; ++i) {
            if (i < na) {                // q = wv_s+4i < len  <=>  i < na
                const int q = wv_s + 4 * i;
                #pragma unroll
                for (int j = 0; j < 4; ++j) {
                    float sim = acc[i][j] * rinv[j];
                    int bin = (int)floorf((sim + 1.0f) * 15.0f);
                    bin = bin < 0 ? 0 : (bin > 29 ? 29 : bin);
                    atomicAdd(&s_hist[q][bin], 1);
                }
            }
        }
    }
    __syncthreads();

    for (int s = tid; s < QQ * NB; s += 256) {
        const int q = s / NB, bin = s % NB;
        int tot = s_hist[q][bin];
        if (tot) atomicAdd(&ghist[((size_t)b * QQ + q) * NB + bin], tot);
    }
}

// ---------------- final: log1p + FFN + softmax gate + weighted sum ----------------
__global__ __launch_bounds__(64) void drmm_final(const int* __restrict__ ghist,
                                                 const float* __restrict__ glog,
                                                 const float* __restrict__ W1,
                                                 const float* __restrict__ b1,
                                                 const float* __restrict__ W2,
                                                 const float* __restrict__ b2,
                                                 const float* __restrict__ W3,
                                                 const float* __restrict__ b3,
                                                 float* __restrict__ out) {
    const int b = blockIdx.x;
    const int lane = threadIdx.x;       // lanes 0..31 carry q
    float z = 0.f, lg = -1e30f;
    if (lane < QQ) {
        const int* hrow = ghist + ((size_t)b * QQ + lane) * NB;
        float h[NB];
        #pragma unroll
        for (int v = 0; v < NB; ++v) h[v] = log1pf((float)hrow[v]);
        float t1[5];
        #pragma unroll
        for (int u = 0; u < 5; ++u) {
            float s = b1[u];
            #pragma unroll
            for (int v = 0; v < NB; ++v) s += W1[u * NB + v] * h[v];
            t1[u] = tanhf(s);
        }
        float s2 = b2[0];
        #pragma unroll
        for (int u = 0; u < 5; ++u) s2 += W2[u] * t1[u];
        z = tanhf(W3[0] * tanhf(s2) + b3[0]);
        lg = glog[b * QQ + lane];
    }
    float m = lg;
    for (int o = 16; o >= 1; o >>= 1) m = fmaxf(m, __shfl_xor(m, o));
    float e = (lane < QQ) ? expf(lg - m) : 0.f;
    float s = e;
    for (int o = 16; o >= 1; o >>= 1) s += __shfl_xor(s, o);
    float w = z * (e / s);
    for (int o = 16; o >= 1; o >>= 1) w += __shfl_xor(w, o);
    if (lane == 0) out[b] = w;
}

extern "C" void kernel_launch(void* const* d_in, const int* in_sizes, int n_in,
                              void* d_out, int out_size, void* d_ws, size_t ws_size,
                              hipStream_t stream) {
    const float* query = (const float*)d_in[0];
    const float* doc   = (const float*)d_in[1];
    const int*   qlen  = (const int*)d_in[2];
    const float* W1    = (const float*)d_in[3];
    const float* b1    = (const float*)d_in[4];
    const float* W2    = (const float*)d_in[5];
    const float* b2    = (const float*)d_in[6];
    const float* W3    = (const float*)d_in[7];
    const float* b3    = (const float*)d_in[8];
    const float* Wg    = (const float*)d_in[9];
    const float* bg    = (const float*)d_in[10];
    float* out = (float*)d_out;

    float* qn   = (float*)d_ws;                       // [64][32][304]
    float* glog = qn + (size_t)BB * QQ * EP;          // [2048]
    int*   hist = (int*)(glog + BB * QQ);             // [64][32][30]

    hipMemsetAsync(hist, 0, (size_t)BB * QQ * NB * sizeof(int), stream);
    hipLaunchKernelGGL(drmm_prep, dim3(BB * QQ), dim3(64), 0, stream,
                       query, Wg, bg, qn, glog);
    hipLaunchKernelGGL(drmm_main, dim3(BB * NDT), dim3(256), 0, stream,
                       doc, qlen, qn, hist);
    hipLaunchKernelGGL(drmm_final, dim3(BB), dim3(64), 0, stream,
                       hist, glog, W1, b1, W2, b2, W3, b3, out);
}

// Round 7
// 112.567 us; speedup vs baseline: 3.7823x; 1.6401x over previous
//
#include <hip/hip_runtime.h>
#include <math.h>

#define BB 64
#define QQ 32
#define DD 4096
#define EE 300
#define EPAD 320         // qn k-padded with zeros to 320 (10 chunks of 32)
#define NB 30
#define WD 64            // doc rows per wave
#define TDB 256          // doc rows per block (4 waves)
#define NDT (DD/TDB)     // 16
#define NCH 10           // K-chunks of 32

typedef __attribute__((ext_vector_type(8))) short short8v;   // 8 bf16 = 1 MFMA frag
typedef __attribute__((ext_vector_type(4))) float f32x4;

// RNE float->bf16 (bit pattern), and bf16->float
static __device__ __forceinline__ unsigned short f2bf(float x) {
    unsigned int u = __builtin_bit_cast(unsigned int, x);
    u = (u + 0x7FFFu + ((u >> 16) & 1u)) >> 16;
    return (unsigned short)u;
}
static __device__ __forceinline__ float bf2f(unsigned short h) {
    return __builtin_bit_cast(float, (unsigned int)h << 16);
}

// ---------------- prep: normalize query, split to bf16 hi/lo frag arrays, gate logits ----
__global__ __launch_bounds__(64) void drmm_prep(const float* __restrict__ query,
                                                const float* __restrict__ Wg,
                                                const float* __restrict__ bg,
                                                unsigned short* __restrict__ qh,
                                                unsigned short* __restrict__ ql,
                                                float* __restrict__ glog) {
    const int row  = blockIdx.x;          // b*32+q
    const int lane = threadIdx.x;         // 0..63
    const float* src = query + (size_t)row * EE;
    float ss = 0.f;
    for (int e = lane; e < EE; e += 64) { float x = src[e]; ss += x * x; }
    for (int o = 1; o < 64; o <<= 1) ss += __shfl_xor(ss, o);
    const float inv = 1.0f / sqrtf(ss);
    float gd = 0.f;
    #pragma unroll
    for (int it = 0; it < 5; ++it) {      // 5*64 = 320 = EPAD
        int e = it * 64 + lane;
        float x = (e < EE) ? src[e] * inv : 0.f;
        unsigned short h = f2bf(x);
        float lo = x - bf2f(h);
        qh[(size_t)row * EPAD + e] = h;
        ql[(size_t)row * EPAD + e] = f2bf(lo);
        if (e < EE) gd += x * Wg[e];
    }
    for (int o = 1; o < 64; o <<= 1) gd += __shfl_xor(gd, o);
    if (lane == 0) glog[row] = gd + bg[0];
}

// ---------------- main: MFMA interaction + histogram ----------------
// 256 threads = 4 waves; wave wv owns doc rows [dt*256 + wv*64, +64) as 4 tiles of 16.
// Per K-chunk (32 e): lane l loads 8 fp32 of doc row (l&15) at k=(l>>4)*8 (two float4),
// splits to bf16 hi/lo in-lane (= B fragment), loads pre-split qn A-fragments from
// global, and accumulates sims via 3-way split MFMA (hi*hi + hi*lo + lo*hi).
// No LDS staging, no barriers in the main loop.
__global__ __launch_bounds__(256, 4) void drmm_main(const float* __restrict__ doc,
                                                    const int* __restrict__ qlen,
                                                    const unsigned short* __restrict__ qh,
                                                    const unsigned short* __restrict__ ql,
                                                    int* __restrict__ ghist) {
    __shared__ int s_hist[QQ][32];        // 4 KB, padded rows

    const int b   = blockIdx.x >> 4;
    const int dt  = blockIdx.x & 15;
    const int len = qlen[b];
    if (len == 0) return;                 // hist stays zero for this b

    const int tid = threadIdx.x;
    const int wv  = tid >> 6;
    const int l15 = tid & 15;             // fragment row index
    const int l4  = (tid >> 4) & 3;       // k-group (0..3)
    const int nqt = (len > 16) ? 2 : 1;   // scalar: q-tiles needed

    for (int s = tid; s < QQ * 32; s += 256) ((int*)s_hist)[s] = 0;

    const float* drow0 = doc + (size_t)(b * DD + dt * TDB + wv * WD + l15) * EE;
    const unsigned short* qhb = qh + ((size_t)b * QQ + l15) * EPAD + l4 * 8;
    const unsigned short* qlb = ql + ((size_t)b * QQ + l15) * EPAD + l4 * 8;

    f32x4 acc[2][4];
    #pragma unroll
    for (int qt = 0; qt < 2; ++qt)
        #pragma unroll
        for (int t = 0; t < 4; ++t) acc[qt][t] = (f32x4){0.f, 0.f, 0.f, 0.f};
    float ssq[4] = {0.f, 0.f, 0.f, 0.f};

    const int kw = l4 * 8;                // lane's k-offset within chunk

    for (int c = 0; c < NCH; ++c) {
        const int kb = c * 32 + kw;       // logical k of this lane's window
        const int k1 = (kb     < EE) ? kb     : 0;   // pad quads redirected in-bounds;
        const int k2 = (kb + 4 < EE) ? kb + 4 : 0;   // their products hit qn pad zeros

        // ---- issue all global loads for this chunk (12 per lane max) ----
        f32x4 v[4][2];
        #pragma unroll
        for (int t = 0; t < 4; ++t) {
            const float* rp = drow0 + (size_t)t * 16 * EE;
            v[t][0] = *(const f32x4*)(rp + k1);
            v[t][1] = *(const f32x4*)(rp + k2);
        }
        short8v ah0 = *(const short8v*)(qhb + c * 32);
        short8v al0 = *(const short8v*)(qlb + c * 32);
        short8v ah1 = {}, al1 = {};
        if (nqt > 1) {
            ah1 = *(const short8v*)(qhb + 16 * EPAD + c * 32);
            al1 = *(const short8v*)(qlb + 16 * EPAD + c * 32);
        }

        const bool r1 = (kb < EE), r2 = (kb + 4 < EE);   // real (non-pad) quads

        #pragma unroll
        for (int t = 0; t < 4; ++t) {
            const f32x4 v0 = v[t][0], v1 = v[t][1];
            if (r1) ssq[t] += v0.x * v0.x + v0.y * v0.y + v0.z * v0.z + v0.w * v0.w;
            if (r2) ssq[t] += v1.x * v1.x + v1.y * v1.y + v1.z * v1.z + v1.w * v1.w;

            short8v bhi, blo;
            #pragma unroll
            for (int j = 0; j < 4; ++j) {
                unsigned short h0 = f2bf(v0[j]);
                unsigned short h1 = f2bf(v1[j]);
                bhi[j]     = (short)h0;
                bhi[j + 4] = (short)h1;
                blo[j]     = (short)f2bf(v0[j] - bf2f(h0));
                blo[j + 4] = (short)f2bf(v1[j] - bf2f(h1));
            }
            acc[0][t] = __builtin_amdgcn_mfma_f32_16x16x32_bf16(ah0, bhi, acc[0][t], 0, 0, 0);
            acc[0][t] = __builtin_amdgcn_mfma_f32_16x16x32_bf16(ah0, blo, acc[0][t], 0, 0, 0);
            acc[0][t] = __builtin_amdgcn_mfma_f32_16x16x32_bf16(al0, bhi, acc[0][t], 0, 0, 0);
            if (nqt > 1) {
                acc[1][t] = __builtin_amdgcn_mfma_f32_16x16x32_bf16(ah1, bhi, acc[1][t], 0, 0, 0);
                acc[1][t] = __builtin_amdgcn_mfma_f32_16x16x32_bf16(ah1, blo, acc[1][t], 0, 0, 0);
                acc[1][t] = __builtin_amdgcn_mfma_f32_16x16x32_bf16(al1, bhi, acc[1][t], 0, 0, 0);
            }
        }
    }

    // full row-norms: combine the 4 k-group partials (lanes l, l^16, l^32)
    float rinv[4];
    #pragma unroll
    for (int t = 0; t < 4; ++t) {
        float s = ssq[t];
        s += __shfl_xor(s, 16);
        s += __shfl_xor(s, 32);
        rinv[t] = 1.0f / sqrtf(s);        // row (l15) of tile t
    }

    __syncthreads();                      // hist zeros visible before atomics

    // D layout (m89-verified): col = lane&15 (= d within tile), row = (lane>>4)*4 + reg (= q)
    #pragma unroll
    for (int qt = 0; qt < 2; ++qt) {
        #pragma unroll
        for (int r = 0; r < 4; ++r) {
            const int q = qt * 16 + l4 * 4 + r;
            if (q < len) {
                #pragma unroll
                for (int t = 0; t < 4; ++t) {
                    float sim = acc[qt][t][r] * rinv[t];
                    int bin = (int)floorf((sim + 1.0f) * 15.0f);
                    bin = bin < 0 ? 0 : (bin > 29 ? 29 : bin);
                    atomicAdd(&s_hist[q][bin], 1);
                }
            }
        }
    }
    __syncthreads();

    for (int s = tid; s < QQ * NB; s += 256) {
        const int q = s / NB, bin = s % NB;
        int tot = s_hist[q][bin];
        if (tot) atomicAdd(&ghist[((size_t)b * QQ + q) * NB + bin], tot);
    }
}

// ---------------- final: log1p + FFN + softmax gate + weighted sum ----------------
__global__ __launch_bounds__(64) void drmm_final(const int* __restrict__ ghist,
                                                 const float* __restrict__ glog,
                                                 const float* __restrict__ W1,
                                                 const float* __restrict__ b1,
                                                 const float* __restrict__ W2,
                                                 const float* __restrict__ b2,
                                                 const float* __restrict__ W3,
                                                 const float* __restrict__ b3,
                                                 float* __restrict__ out) {
    const int b = blockIdx.x;
    const int lane = threadIdx.x;         // lanes 0..31 carry q
    float z = 0.f, lg = -1e30f;
    if (lane < QQ) {
        const int* hrow = ghist + ((size_t)b * QQ + lane) * NB;
        float h[NB];
        #pragma unroll
        for (int v = 0; v < NB; ++v) h[v] = log1pf((float)hrow[v]);
        float t1[5];
        #pragma unroll
        for (int u = 0; u < 5; ++u) {
            float s = b1[u];
            #pragma unroll
            for (int v = 0; v < NB; ++v) s += W1[u * NB + v] * h[v];
            t1[u] = tanhf(s);
        }
        float s2 = b2[0];
        #pragma unroll
        for (int u = 0; u < 5; ++u) s2 += W2[u] * t1[u];
        z = tanhf(W3[0] * tanhf(s2) + b3[0]);
        lg = glog[b * QQ + lane];
    }
    float m = lg;
    for (int o = 16; o >= 1; o >>= 1) m = fmaxf(m, __shfl_xor(m, o));
    float e = (lane < QQ) ? expf(lg - m) : 0.f;
    float s = e;
    for (int o = 16; o >= 1; o >>= 1) s += __shfl_xor(s, o);
    float w = z * (e / s);
    for (int o = 16; o >= 1; o >>= 1) w += __shfl_xor(w, o);
    if (lane == 0) out[b] = w;
}

extern "C" void kernel_launch(void* const* d_in, const int* in_sizes, int n_in,
                              void* d_out, int out_size, void* d_ws, size_t ws_size,
                              hipStream_t stream) {
    const float* query = (const float*)d_in[0];
    const float* doc   = (const float*)d_in[1];
    const int*   qlen  = (const int*)d_in[2];
    const float* W1    = (const float*)d_in[3];
    const float* b1    = (const float*)d_in[4];
    const float* W2    = (const float*)d_in[5];
    const float* b2    = (const float*)d_in[6];
    const float* W3    = (const float*)d_in[7];
    const float* b3    = (const float*)d_in[8];
    const float* Wg    = (const float*)d_in[9];
    const float* bg    = (const float*)d_in[10];
    float* out = (float*)d_out;

    unsigned short* qh = (unsigned short*)d_ws;            // [2048][320] bf16 hi
    unsigned short* ql = qh + (size_t)BB * QQ * EPAD;      // [2048][320] bf16 lo
    float* glog = (float*)(ql + (size_t)BB * QQ * EPAD);   // [2048]
    int*   hist = (int*)(glog + BB * QQ);                  // [64][32][30]

    hipMemsetAsync(hist, 0, (size_t)BB * QQ * NB * sizeof(int), stream);
    hipLaunchKernelGGL(drmm_prep, dim3(BB * QQ), dim3(64), 0, stream,
                       query, Wg, bg, qh, ql, glog);
    hipLaunchKernelGGL(drmm_main, dim3(BB * NDT), dim3(256), 0, stream,
                       doc, qlen, qh, ql, hist);
    hipLaunchKernelGGL(drmm_final, dim3(BB), dim3(64), 0, stream,
                       hist, glog, W1, b1, W2, b2, W3, b3, out);
}